// Round 5
// baseline (408.751 us; speedup 1.0000x reference)
//
#include <hip/hip_runtime.h>
#include <stdint.h>

#define T_TOK 8192
#define NEXP  8
#define DIMSZ 1024
#define HIDSZ 2048

typedef __attribute__((ext_vector_type(4))) float f32x4;
typedef __attribute__((ext_vector_type(8))) short s16x8;

// ---------- helpers ----------

__device__ __forceinline__ uint16_t f2bf(float f) {
  uint32_t u = __builtin_bit_cast(uint32_t, f);
  u += 0x7fffu + ((u >> 16) & 1u);   // RNE
  return (uint16_t)(u >> 16);
}

#if __has_builtin(__builtin_amdgcn_cvt_pk_bf16_f32)
typedef __attribute__((ext_vector_type(2))) __bf16 bf16x2;
__device__ __forceinline__ uint32_t pk2(float a, float b) {
  bf16x2 r = __builtin_amdgcn_cvt_pk_bf16_f32(a, b);   // v_cvt_pk_bf16_f32 (RNE)
  return __builtin_bit_cast(uint32_t, r);
}
#else
__device__ __forceinline__ uint32_t pk2(float a, float b) {
  return (uint32_t)f2bf(a) | ((uint32_t)f2bf(b) << 16);
}
#endif

// ---------- offsets ----------

__global__ void offs_kernel(const int* __restrict__ counts, int* __restrict__ offs,
                            int* __restrict__ toffs) {
  if (threadIdx.x == 0) {
    int s = 0, ts = 0;
    for (int e = 0; e < NEXP; ++e) {
      offs[e] = s; toffs[e] = ts;
      s += counts[e]; ts += (counts[e] + 127) >> 7;
    }
    offs[NEXP] = s; toffs[NEXP] = ts;
  }
}

// ---------- grouped NT GEMM, reg-staged pipeline ----------
// C[m,n] = sum_k A[m,k] * B_e[n,k].  Tile 128x128, BK=32, 4 waves (2x2).
// A: f32 (GEMM1, x) or bf16 (GEMM2, h) -- converted/staged through VGPRs.
// B: f32 weights, converted in-flight via v_cvt_pk_bf16_f32.
// Pipeline: loads for tile k+1 issue right after the staging barrier and are
// only waited at iteration k+1's ds_write -> latency overlaps compute (the
// R4 counters showed the global_load_lds vmcnt(0)+barrier drain cost ~2300
// cyc/iter at low occupancy).
// XCD supertiling (R4: FETCH = compulsory): xcd = b&7 owns an (m-group,
// n-group) region; m-tiles stride-interleaved across m-groups for balance.
// LDS chunk-swizzle (R3: conflicts = 0): global 16B-chunk q of row r lives
// at chunk q ^ ((r>>1)&3).
template <bool A_BF16, bool OUT_BF16>
__global__ __launch_bounds__(256, 3)
void gemm_grouped(const void* __restrict__ Av, const float* __restrict__ Bf,
                  void* __restrict__ C, const int* __restrict__ offs,
                  const int* __restrict__ toffs, int N, int K,
                  int mgs, int ntg, int ngx, int ngm) {
  __shared__ __align__(16) uint16_t As[128 * 32];  // 8 KB
  __shared__ __align__(16) uint16_t Bs[128 * 32];  // 8 KB

  const int xcd  = blockIdx.x & 7;
  const int slot = blockIdx.x >> 3;
  const int mg = xcd / ngx, ng = xcd % ngx;
  const int mtg = mg + ngm * (slot % mgs);         // stride-interleaved m-tiles
  const int nt  = ng * ntg + slot / mgs;
  if (mtg >= toffs[NEXP]) return;
  int e = 0;
#pragma unroll
  for (int i = 1; i < NEXP; ++i) e += (toffs[i] <= mtg) ? 1 : 0;
  const int mt      = mtg - toffs[e];
  const int m_start = offs[e];
  const int m_count = offs[e + 1] - m_start;
  const int m0      = mt * 128;
  int valid_m = m_count - m0;
  if (valid_m > 128) valid_m = 128;
  const int n0 = nt * 128;

  const int tid  = threadIdx.x;
  const int lane = tid & 63;
  const int w    = tid >> 6;
  const int wm = w & 1, wn = w >> 1;

  // Staging map: thread t owns 16B-bf16 chunks (r0,qc) and (r1,qc).
  const int r0 = tid >> 2;          // 0..63
  const int r1 = r0 + 64;           // 64..127
  const int qc = tid & 3;
  const int s0 = (r0 >> 1) & 3, s1 = (r1 >> 1) & 3;
  uint16_t* wA0 = &As[r0 * 32 + (qc ^ s0) * 8];
  uint16_t* wA1 = &As[r1 * 32 + (qc ^ s1) * 8];
  uint16_t* wB0 = &Bs[r0 * 32 + (qc ^ s0) * 8];
  uint16_t* wB1 = &Bs[r1 * 32 + (qc ^ s1) * 8];

  // Global rows (A clamped for ragged tail; dup rows computed, never stored).
  const int ar0 = m_start + m0 + (r0 < valid_m ? r0 : valid_m - 1);
  const int ar1 = m_start + m0 + (r1 < valid_m ? r1 : valid_m - 1);

  const float*    aF0 = nullptr; const float*    aF1 = nullptr;
  const uint16_t* aH0 = nullptr; const uint16_t* aH1 = nullptr;
  if constexpr (A_BF16) {
    aH0 = (const uint16_t*)Av + (size_t)ar0 * K + qc * 8;
    aH1 = (const uint16_t*)Av + (size_t)ar1 * K + qc * 8;
  } else {
    aF0 = (const float*)Av + (size_t)ar0 * K + qc * 8;
    aF1 = (const float*)Av + (size_t)ar1 * K + qc * 8;
  }
  const float* bP0 = Bf + ((size_t)e * N + n0 + r0) * K + qc * 8;
  const float* bP1 = Bf + ((size_t)e * N + n0 + r1) * K + qc * 8;

  // Staging registers.
  f32x4 a_f[4]; uint4 a_h[2]; f32x4 b_f[4];

  auto load_tiles = [&]() {
    if constexpr (A_BF16) {
      a_h[0] = *(const uint4*)aH0;
      a_h[1] = *(const uint4*)aH1;
      aH0 += 32; aH1 += 32;
    } else {
      a_f[0] = *(const f32x4*)aF0; a_f[1] = *(const f32x4*)(aF0 + 4);
      a_f[2] = *(const f32x4*)aF1; a_f[3] = *(const f32x4*)(aF1 + 4);
      aF0 += 32; aF1 += 32;
    }
    b_f[0] = *(const f32x4*)bP0; b_f[1] = *(const f32x4*)(bP0 + 4);
    b_f[2] = *(const f32x4*)bP1; b_f[3] = *(const f32x4*)(bP1 + 4);
    bP0 += 32; bP1 += 32;
  };

  auto store_lds = [&]() {
    if constexpr (A_BF16) {
      *(uint4*)wA0 = a_h[0];
      *(uint4*)wA1 = a_h[1];
    } else {
      *(uint4*)wA0 = make_uint4(pk2(a_f[0][0], a_f[0][1]), pk2(a_f[0][2], a_f[0][3]),
                                pk2(a_f[1][0], a_f[1][1]), pk2(a_f[1][2], a_f[1][3]));
      *(uint4*)wA1 = make_uint4(pk2(a_f[2][0], a_f[2][1]), pk2(a_f[2][2], a_f[2][3]),
                                pk2(a_f[3][0], a_f[3][1]), pk2(a_f[3][2], a_f[3][3]));
    }
    *(uint4*)wB0 = make_uint4(pk2(b_f[0][0], b_f[0][1]), pk2(b_f[0][2], b_f[0][3]),
                              pk2(b_f[1][0], b_f[1][1]), pk2(b_f[1][2], b_f[1][3]));
    *(uint4*)wB1 = make_uint4(pk2(b_f[2][0], b_f[2][1]), pk2(b_f[2][2], b_f[2][3]),
                              pk2(b_f[3][0], b_f[3][1]), pk2(b_f[3][2], b_f[3][3]));
  };

  // Fragment addresses (swizzled): k-chunk q=lane>>4 is at chunk q^((fr>>1)&3).
  const int fr = lane & 15;
  const int fk = ((lane >> 4) ^ ((fr >> 1) & 3)) * 8;

  f32x4 acc[4][4];
#pragma unroll
  for (int mi = 0; mi < 4; ++mi)
#pragma unroll
    for (int ni = 0; ni < 4; ++ni) acc[mi][ni] = (f32x4){0.f, 0.f, 0.f, 0.f};

  load_tiles();                       // prologue: tile 0 in flight
  const int iters = K >> 5;
  for (int it = 0; it < iters; ++it) {
    __syncthreads();                  // LDS reads of it-1 complete
    store_lds();                      // waits vmcnt for this tile's loads
    __syncthreads();                  // tiles resident
    if (it + 1 < iters) load_tiles(); // prefetch: drains only at next store_lds

    s16x8 af[4], bf[4];
#pragma unroll
    for (int mi = 0; mi < 4; ++mi)
      af[mi] = *(const s16x8*)&As[(wm * 64 + mi * 16 + fr) * 32 + fk];
#pragma unroll
    for (int ni = 0; ni < 4; ++ni)
      bf[ni] = *(const s16x8*)&Bs[(wn * 64 + ni * 16 + fr) * 32 + fk];
#pragma unroll
    for (int mi = 0; mi < 4; ++mi)
#pragma unroll
      for (int ni = 0; ni < 4; ++ni)
        acc[mi][ni] = __builtin_amdgcn_mfma_f32_16x16x32_bf16(af[mi], bf[ni], acc[mi][ni], 0, 0, 0);
  }

  // Epilogue. C/D 16x16 layout: col = lane&15, row = (lane>>4)*4 + reg.
  const int cq = (lane >> 4) * 4;
  const int cc = lane & 15;
#pragma unroll
  for (int mi = 0; mi < 4; ++mi) {
#pragma unroll
    for (int r = 0; r < 4; ++r) {
      const int rt = wm * 64 + mi * 16 + cq + r;
      if (rt < valid_m) {
        const size_t rowoff = (size_t)(m_start + m0 + rt) * N;
#pragma unroll
        for (int ni = 0; ni < 4; ++ni) {
          const int col = n0 + wn * 64 + ni * 16 + cc;
          const float v = acc[mi][ni][r];
          if (OUT_BF16) {
            ((uint16_t*)C)[rowoff + col] = f2bf(v);
          } else {
            const uint32_t b = (uint32_t)f2bf(v) << 16;  // ref: value went thru bf16
            ((float*)C)[rowoff + col] = __builtin_bit_cast(float, b);
          }
        }
      }
    }
  }
}

// ---------- launch ----------

extern "C" void kernel_launch(void* const* d_in, const int* in_sizes, int n_in,
                              void* d_out, int out_size, void* d_ws, size_t ws_size,
                              hipStream_t stream) {
  const float* x  = (const float*)d_in[0];   // [T, DIM] f32
  const float* w1 = (const float*)d_in[1];   // [E, HID, DIM] f32
  const float* w2 = (const float*)d_in[2];   // [E, DIM, HID] f32
  const int* cnt  = (const int*)d_in[3];     // [E]
  float* out = (float*)d_out;                // [T, DIM] f32

  char* ws = (char*)d_ws;
  uint16_t* h = (uint16_t*)ws;               // 32 MB  [T, HID] bf16
  int* offs   = (int*)(ws + 33554432);       // 9 ints
  int* toffs  = offs + 9;                    // 9 ints

  offs_kernel<<<1, 64, 0, stream>>>(cnt, offs, toffs);

  // GEMM1: h = bf16(x) @ bf16(w1)^T  (N=HID, 16 nt, K=DIM).
  //   XCDs: 4 m-groups x 2 n-groups; mgs=18 (4*18=72>=71), ntg=8.
  gemm_grouped<false, true><<<8 * 18 * 8, 256, 0, stream>>>(
      (const void*)x, w1, (void*)h, offs, toffs, HIDSZ, DIMSZ, 18, 8, 2, 4);

  // GEMM2: out = h @ bf16(w2)^T  (N=DIM, 8 nt, K=HID).
  //   XCDs: 8 m-groups x 1 n-group; mgs=9 (8*9=72>=71), ntg=8.
  gemm_grouped<true, false><<<8 * 9 * 8, 256, 0, stream>>>(
      (const void*)h, w2, (void*)out, offs, toffs, DIMSZ, HIDSZ, 9, 8, 1, 8);
}

// Round 6
// 289.973 us; speedup vs baseline: 1.4096x; 1.4096x over previous
//
#include <hip/hip_runtime.h>
#include <stdint.h>

#define T_TOK 8192
#define NEXP  8
#define DIMSZ 1024
#define HIDSZ 2048
#define BK    64

typedef __attribute__((ext_vector_type(4))) float f32x4;
typedef __attribute__((ext_vector_type(8))) short s16x8;

// ---------- helpers ----------

__device__ __forceinline__ uint16_t f2bf(float f) {
  uint32_t u = __builtin_bit_cast(uint32_t, f);
  u += 0x7fffu + ((u >> 16) & 1u);   // RNE
  return (uint16_t)(u >> 16);
}

// async global->LDS, 16B per lane; HW writes base + lane*16 (wave-uniform base).
__device__ __forceinline__ void gload_lds16(const uint16_t* g, const uint16_t* lds_base) {
  __builtin_amdgcn_global_load_lds(
      (const __attribute__((address_space(1))) uint32_t*)(uintptr_t)g,
      (__attribute__((address_space(3))) uint32_t*)(uint32_t)(uintptr_t)lds_base,
      16, 0, 0);
}

// ---------- fused convert (+ offsets in block 0) ----------
// unit = 8 floats: 2 x float4 load -> 1 x uint4 (16B) store, full store width.
// 2560 blocks x 256 threads x 8 units. Regions: x | w1 | w2.

__global__ void cvt_all(const float* __restrict__ x, const float* __restrict__ w1,
                        const float* __restrict__ w2, uint16_t* __restrict__ xb,
                        uint16_t* __restrict__ w1b, uint16_t* __restrict__ w2b,
                        const int* __restrict__ counts, int* __restrict__ offs,
                        int* __restrict__ toffs) {
  if (blockIdx.x == 0 && threadIdx.x == 0) {
    int s = 0, ts = 0;
    for (int e = 0; e < NEXP; ++e) {
      offs[e] = s; toffs[e] = ts;
      s += counts[e]; ts += (counts[e] + 127) >> 7;
    }
    offs[NEXP] = s; toffs[NEXP] = ts;
  }
  const int b = blockIdx.x;
  const float4* src; uint4* dst; size_t base;     // base in 8-float units
  if (b < 512)       { src = (const float4*)x;  dst = (uint4*)xb;  base = (size_t)b * 2048; }
  else if (b < 1536) { src = (const float4*)w1; dst = (uint4*)w1b; base = (size_t)(b - 512) * 2048; }
  else               { src = (const float4*)w2; dst = (uint4*)w2b; base = (size_t)(b - 1536) * 2048; }

#pragma unroll
  for (int half = 0; half < 2; ++half) {
    const size_t u0 = base + (size_t)half * 1024 + threadIdx.x;
    float4 v[8];
#pragma unroll
    for (int j = 0; j < 4; ++j) {
      v[2 * j]     = src[2 * (u0 + j * 256)];
      v[2 * j + 1] = src[2 * (u0 + j * 256) + 1];
    }
#pragma unroll
    for (int j = 0; j < 4; ++j) {
      uint4 o;
      o.x = f2bf(v[2 * j].x)     | ((uint32_t)f2bf(v[2 * j].y) << 16);
      o.y = f2bf(v[2 * j].z)     | ((uint32_t)f2bf(v[2 * j].w) << 16);
      o.z = f2bf(v[2 * j + 1].x) | ((uint32_t)f2bf(v[2 * j + 1].y) << 16);
      o.w = f2bf(v[2 * j + 1].z) | ((uint32_t)f2bf(v[2 * j + 1].w) << 16);
      dst[u0 + j * 256] = o;
    }
  }
}

// ---------- grouped NT GEMM, BK=64 ----------
// C[m,n] = sum_k A[m,k] * B_e[n,k].  Tile 128x128, BK=64, 4 waves (2x2),
// 32 MFMA per barrier pair (2x the R4 amortization of the vmcnt(0) drain).
// Staging: 4 global_load_lds_dwordx4 per matrix per thread per iter; LDS slot
// s = q*256 + tid holds row r = s/8, chunk-pos p = s%8, which stores GLOBAL
// chunk g = p ^ (r&7)  (swizzle absorbed into the global source address since
// the DMA forces lds = base + lane*16).  Fragment ds_read_b128 then hits each
// bank-group 2-way (free, m136).  XCD supertile as R4 (FETCH == compulsory).
template <bool OUT_BF16>
__global__ __launch_bounds__(256, 4)
void gemm_grouped(const uint16_t* __restrict__ A, const uint16_t* __restrict__ B,
                  void* __restrict__ C, const int* __restrict__ offs,
                  const int* __restrict__ toffs, int N, int K,
                  int mgs, int ntg, int ngx) {
  __shared__ __align__(16) uint16_t As[128 * BK];  // 16 KB
  __shared__ __align__(16) uint16_t Bs[128 * BK];  // 16 KB

  const int xcd  = blockIdx.x & 7;
  const int slot = blockIdx.x >> 3;
  const int mg = xcd / ngx, ng = xcd % ngx;
  const int mtg = mg * mgs + slot % mgs;
  const int nt  = ng * ntg + slot / mgs;
  if (mtg >= toffs[NEXP]) return;
  int e = 0;
#pragma unroll
  for (int i = 1; i < NEXP; ++i) e += (toffs[i] <= mtg) ? 1 : 0;
  const int mt      = mtg - toffs[e];
  const int m_start = offs[e];
  const int m_count = offs[e + 1] - m_start;
  const int m0      = mt * 128;
  int valid_m = m_count - m0;
  if (valid_m > 128) valid_m = 128;
  const int n0 = nt * 128;

  const int tid  = threadIdx.x;
  const int lane = tid & 63;
  const int w    = tid >> 6;
  const int wm = w & 1, wn = w >> 1;

  // Staging thread map: per call q, this thread supplies row q*32 + srow,
  // global 16B chunk gch (swizzled), landing at LDS slot q*256 + tid.
  const int srow = tid >> 3;                       // 0..31
  const int gch  = (tid & 7) ^ (srow & 7);         // swizzle
  const uint16_t* gB = B + (size_t)e * N * K;
  const uint16_t* gA = A + (size_t)m_start * K;

  const uint16_t* aP[4];
  const uint16_t* bP[4];
#pragma unroll
  for (int q = 0; q < 4; ++q) {
    const int rq = q * 32 + srow;
    const int ar = m0 + (rq < valid_m ? rq : valid_m - 1);  // ragged-tail clamp
    aP[q] = gA + (size_t)ar * K + gch * 8;
    bP[q] = gB + (size_t)(n0 + q * 32 + srow) * K + gch * 8;
  }

  // Fragment addresses: row r = band + fr, k-halves t=0,1 want byte-chunk
  // t*4 + (lane>>4), stored at pos ^ (fr&7).
  const int fr = lane & 15;
  const int q4 = lane >> 4;
  const int pA0 = ((q4)     ^ (fr & 7)) * 8;       // elems
  const int pA1 = ((4 + q4) ^ (fr & 7)) * 8;

  f32x4 acc[4][4];
#pragma unroll
  for (int mi = 0; mi < 4; ++mi)
#pragma unroll
    for (int ni = 0; ni < 4; ++ni) acc[mi][ni] = (f32x4){0.f, 0.f, 0.f, 0.f};

  for (int k0 = 0; k0 < K; k0 += BK) {
    __syncthreads();
#pragma unroll
    for (int q = 0; q < 4; ++q) {
      gload_lds16(aP[q], As + q * 2048 + w * 512);
      gload_lds16(bP[q], Bs + q * 2048 + w * 512);
      aP[q] += BK; bP[q] += BK;
    }
    __syncthreads();

    s16x8 af[4][2], bf[4][2];
#pragma unroll
    for (int mi = 0; mi < 4; ++mi) {
      const int r = (wm * 64 + mi * 16 + fr) * BK;
      af[mi][0] = *(const s16x8*)&As[r + pA0];
      af[mi][1] = *(const s16x8*)&As[r + pA1];
    }
#pragma unroll
    for (int ni = 0; ni < 4; ++ni) {
      const int r = (wn * 64 + ni * 16 + fr) * BK;
      bf[ni][0] = *(const s16x8*)&Bs[r + pA0];
      bf[ni][1] = *(const s16x8*)&Bs[r + pA1];
    }
#pragma unroll
    for (int t = 0; t < 2; ++t)
#pragma unroll
      for (int mi = 0; mi < 4; ++mi)
#pragma unroll
        for (int ni = 0; ni < 4; ++ni)
          acc[mi][ni] = __builtin_amdgcn_mfma_f32_16x16x32_bf16(af[mi][t], bf[ni][t], acc[mi][ni], 0, 0, 0);
  }

  // Epilogue. C/D 16x16 layout: col = lane&15, row = (lane>>4)*4 + reg.
  const int cq = (lane >> 4) * 4;
  const int cc = lane & 15;
#pragma unroll
  for (int mi = 0; mi < 4; ++mi) {
#pragma unroll
    for (int r = 0; r < 4; ++r) {
      const int rt = wm * 64 + mi * 16 + cq + r;
      if (rt < valid_m) {
        const size_t rowoff = (size_t)(m_start + m0 + rt) * N;
#pragma unroll
        for (int ni = 0; ni < 4; ++ni) {
          const int col = n0 + wn * 64 + ni * 16 + cc;
          const float v = acc[mi][ni][r];
          if (OUT_BF16) {
            ((uint16_t*)C)[rowoff + col] = f2bf(v);
          } else {
            const uint32_t bb = (uint32_t)f2bf(v) << 16;  // ref rounds thru bf16
            ((float*)C)[rowoff + col] = __builtin_bit_cast(float, bb);
          }
        }
      }
    }
  }
}

// ---------- launch ----------

extern "C" void kernel_launch(void* const* d_in, const int* in_sizes, int n_in,
                              void* d_out, int out_size, void* d_ws, size_t ws_size,
                              hipStream_t stream) {
  const float* x  = (const float*)d_in[0];   // [T, DIM]
  const float* w1 = (const float*)d_in[1];   // [E, HID, DIM]
  const float* w2 = (const float*)d_in[2];   // [E, DIM, HID]
  const int* cnt  = (const int*)d_in[3];     // [E]
  float* out = (float*)d_out;                // [T, DIM] f32

  char* ws = (char*)d_ws;
  uint16_t* xb  = (uint16_t*)(ws);                      // 16 MB  [T, DIM] bf16
  uint16_t* w1b = (uint16_t*)(ws + 16777216);           // 32 MB  [E, HID, DIM] bf16
  uint16_t* w2b = (uint16_t*)(ws + 50331648);           // 32 MB  [E, DIM, HID] bf16
  uint16_t* h   = (uint16_t*)(ws + 83886080);           // 32 MB  [T, HID] bf16
  int* offs     = (int*)(ws + 117440512);               // 9 ints
  int* toffs    = offs + 9;                             // 9 ints

  cvt_all<<<2560, 256, 0, stream>>>(x, w1, w2, xb, w1b, w2b, cnt, offs, toffs);

  // GEMM1: h = xb @ w1b^T  (N=HID, 16 nt, K=DIM).  4 m-groups x 2 n-groups.
  gemm_grouped<true><<<8 * 18 * 8, 256, 0, stream>>>(
      xb, w1b, (void*)h, offs, toffs, HIDSZ, DIMSZ, 18, 8, 2);

  // GEMM2: out = h @ w2b^T  (N=DIM, 8 nt, K=HID).  8 m-groups x 1 n-group.
  gemm_grouped<false><<<8 * 9 * 8, 256, 0, stream>>>(
      h, w2b, (void*)out, offs, toffs, DIMSZ, HIDSZ, 9, 8, 1);
}